// Round 3
// baseline (557.497 us; speedup 1.0000x reference)
//
#include <hip/hip_runtime.h>

// Problem constants
#define N_PTS   65536      // B*H*W = 64*32*32
#define K_CODES 1024
#define C_DIM   64
#define HW      1024       // H*W
#define Q_ELEMS 4194304    // 64*64*32*32

// d_out layout (float32): [vq_loss(1) | quantized(4194304) | perplexity(1) | indices(65536)]
#define OUT_Q_OFF 1
#define OUT_P_OFF 4194305
#define OUT_I_OFF 4194306

// ws layout (bytes)
#define WS_HIST 0          // 1024 u32   (4096 B)
#define WS_SSE  4096       // 1 double   (8 B)
#define WS_CSUM 8192       // 1024 float (4096 B)

// numpy pairwise sum (n=64): 8 accumulators striding by 8, then
// ((r0+r1)+(r2+r3))+((r4+r5)+(r6+r7)). All roundings explicit f32.
__device__ __forceinline__ float np_pairwise_sumsq64(const float* __restrict__ a) {
    float r[8];
    #pragma unroll
    for (int j = 0; j < 8; ++j) r[j] = __fmul_rn(a[j], a[j]);
    #pragma unroll
    for (int i = 8; i < 64; i += 8) {
        #pragma unroll
        for (int j = 0; j < 8; ++j)
            r[j] = __fadd_rn(r[j], __fmul_rn(a[i + j], a[i + j]));
    }
    return __fadd_rn(__fadd_rn(__fadd_rn(r[0], r[1]), __fadd_rn(r[2], r[3])),
                     __fadd_rn(__fadd_rn(r[4], r[5]), __fadd_rn(r[6], r[7])));
}

// Prep: B_k = pairwise-f32 sum of codebook row squares.
__global__ void vq_prep(const float* __restrict__ cb, float* __restrict__ csum) {
    int k = blockIdx.x * blockDim.x + threadIdx.x;
    if (k < K_CODES) csum[k] = np_pairwise_sumsq64(cb + k * C_DIM);
}

// Main: split-K. Block = 4 waves x 64 lanes; lane = point within block's
// 64-point group; wave w scans codes [256w, 256w+256). Distances are
// bit-identical to the reference's f32 pipeline:
//   dist = fl32( fl32(A_n + B_k) - fl32(2 * seqFMA_d(x_d * c_kd)) )
// Merge partial argmins lexicographically on (dist, k) -> global first-min.
// Then the block emits indices, histogram, SSE, and the quantized slice.
__global__ __launch_bounds__(256, 4) void vq_main(
        const float* __restrict__ latents,
        const float* __restrict__ cb,
        const float* __restrict__ csum,
        unsigned int* __restrict__ hist,
        double* __restrict__ sse,
        float* __restrict__ out) {
    const int lane = threadIdx.x & 63;
    const int wave = threadIdx.x >> 6;
    const int n  = blockIdx.x * 64 + lane;   // point id; block spans one b
    const int b  = n >> 10;
    const int hw = n & 1023;

    // x_flat[n][d] = latents[b][d][hw]; consecutive lanes -> consecutive hw
    const float* xb = latents + (size_t)b * C_DIM * HW + hw;
    float x[C_DIM];
    #pragma unroll
    for (int d = 0; d < C_DIM; ++d) x[d] = xb[(size_t)d * HW];

    const float A = np_pairwise_sumsq64(x);

    float best = 3.0e38f;
    int bidx = 0;
    const int k0 = wave << 8;                 // 256-code slice per wave
    for (int kk = 0; kk < 256; ++kk) {
        const int k = k0 + kk;
        const float* cbk = cb + (k << 6);     // wave-uniform -> scalar loads
        float m = 0.0f;                       // sequential ascending-d FMA chain
        #pragma unroll
        for (int d = 0; d < C_DIM; ++d) m = __fmaf_rn(x[d], cbk[d], m);
        float dist = __fsub_rn(__fadd_rn(A, csum[k]), __fmul_rn(2.0f, m));
        bool lt = dist < best;                // strict <: first-min within slice
        bidx = lt ? k : bidx;
        best = lt ? dist : best;
    }

    __shared__ float sd[4][64];
    __shared__ int   sk[4][64];
    __shared__ int   fk[64];
    sd[wave][lane] = best;
    sk[wave][lane] = bidx;
    __syncthreads();

    if (wave == 0) {
        float bd = sd[0][lane];
        int   bk = sk[0][lane];
        #pragma unroll
        for (int w = 1; w < 4; ++w) {
            float d2 = sd[w][lane];
            int   k2 = sk[w][lane];
            if (d2 < bd || (d2 == bd && k2 < bk)) { bd = d2; bk = k2; }
        }
        fk[lane] = bk;
        out[OUT_I_OFF + n] = (float)bk;       // 64 contiguous floats per block
        atomicAdd(&hist[bk], 1u);

        // SSE contribution in f64
        const float* cq = cb + (bk << 6);
        double e = 0.0;
        #pragma unroll
        for (int d = 0; d < C_DIM; ++d) {
            double df = (double)x[d] - (double)cq[d];
            e = fma(df, df, e);
        }
        #pragma unroll
        for (int off = 32; off > 0; off >>= 1) e += __shfl_down(e, off, 64);
        if (lane == 0) atomicAdd(sse, e);
    }
    __syncthreads();

    // Quantized slice: out[b][c][hwp] = cb[fk[hwp]][c], 64 c x 64 hw.
    // Thread t: hwp fixed = lane, c = wave + 4*i -> stores contiguous in hw.
    const int myk = fk[lane];
    const size_t obase = (size_t)OUT_Q_OFF + (size_t)b * (C_DIM * HW) + hw;
    #pragma unroll
    for (int i = 0; i < 16; ++i) {
        int c = wave + (i << 2);
        out[obase + (size_t)c * HW] = cb[(myk << 6) + c];
    }
}

// Finalize: perplexity from histogram, vq_loss from SSE.
__global__ void vq_final(const unsigned int* __restrict__ hist,
                         const double* __restrict__ sse,
                         float* __restrict__ out) {
    __shared__ double red[256];
    int t = threadIdx.x;
    double s = 0.0;
    for (int i = t; i < K_CODES; i += 256) {
        double p = (double)hist[i] / (double)N_PTS;
        s += p * log(p + 1e-10);
    }
    red[t] = s;
    __syncthreads();
    for (int w = 128; w > 0; w >>= 1) {
        if (t < w) red[t] += red[t + w];
        __syncthreads();
    }
    if (t == 0) {
        out[OUT_P_OFF] = (float)exp(-red[0]);
        out[0] = (float)(1.25 * sse[0] / (double)Q_ELEMS);
    }
}

extern "C" void kernel_launch(void* const* d_in, const int* in_sizes, int n_in,
                              void* d_out, int out_size, void* d_ws, size_t ws_size,
                              hipStream_t stream) {
    const float* latents = (const float*)d_in[0];
    const float* cb      = (const float*)d_in[1];
    float* out = (float*)d_out;
    char* ws = (char*)d_ws;

    unsigned int* hist = (unsigned int*)(ws + WS_HIST);
    double*       sse  = (double*)(ws + WS_SSE);
    float*        csum = (float*)(ws + WS_CSUM);

    // zero histogram + sse accumulator (contiguous at ws start)
    hipMemsetAsync(ws, 0, 4096 + 8, stream);

    vq_prep <<<4, 256, 0, stream>>>(cb, csum);
    vq_main <<<N_PTS / 64, 256, 0, stream>>>(latents, cb, csum, hist, sse, out);
    vq_final<<<1, 256, 0, stream>>>(hist, sse, out);
}

// Round 4
// 232.257 us; speedup vs baseline: 2.4003x; 2.4003x over previous
//
#include <hip/hip_runtime.h>

// Problem constants
#define N_PTS   65536      // B*H*W = 64*32*32
#define K_CODES 1024
#define C_DIM   64
#define HW      1024       // H*W
#define Q_ELEMS 4194304    // 64*64*32*32

// d_out layout (float32): [vq_loss(1) | quantized(4194304) | perplexity(1) | indices(65536)]
#define OUT_Q_OFF 1
#define OUT_P_OFF 4194305
#define OUT_I_OFF 4194306

// ws layout (bytes)
#define WS_HIST 0          // 1024 u32   (4096 B)
#define WS_SSE  4096       // 1 double   (8 B)
#define WS_CSUM 8192       // 1024 float (4096 B)

// numpy pairwise sum (n=64): 8 accumulators striding by 8, then
// ((r0+r1)+(r2+r3))+((r4+r5)+(r6+r7)). All roundings explicit f32.
__device__ __forceinline__ float np_pairwise_sumsq64(const float* __restrict__ a) {
    float r[8];
    #pragma unroll
    for (int j = 0; j < 8; ++j) r[j] = __fmul_rn(a[j], a[j]);
    #pragma unroll
    for (int i = 8; i < 64; i += 8) {
        #pragma unroll
        for (int j = 0; j < 8; ++j)
            r[j] = __fadd_rn(r[j], __fmul_rn(a[i + j], a[i + j]));
    }
    return __fadd_rn(__fadd_rn(__fadd_rn(r[0], r[1]), __fadd_rn(r[2], r[3])),
                     __fadd_rn(__fadd_rn(r[4], r[5]), __fadd_rn(r[6], r[7])));
}

// Prep: B_k = pairwise-f32 sum of codebook row squares.
__global__ void vq_prep(const float* __restrict__ cb, float* __restrict__ csum) {
    int k = blockIdx.x * blockDim.x + threadIdx.x;
    if (k < K_CODES) csum[k] = np_pairwise_sumsq64(cb + k * C_DIM);
}

// Main: split-K across waves. Block = 4 waves x 64 lanes; lane = point within
// the block's 64-point group; wave w scans codes [256w, 256w+256).
// CRITICAL: k0 goes through readfirstlane so the codebook/csum addresses are
// compiler-provably wave-uniform -> scalar (s_load) path, not per-lane VMEM.
// Distances replicate the reference's f32 pipeline bit-exactly:
//   dist = fl32( fl32(A_n + B_k) - fl32(2 * seqFMA_d(x_d * c_kd)) )
// Partial argmins merge lexicographically on (dist, k) -> global first-min.
__global__ __launch_bounds__(256, 4) void vq_main(
        const float* __restrict__ latents,
        const float* __restrict__ cb,
        const float* __restrict__ csum,
        unsigned int* __restrict__ hist,
        double* __restrict__ sse,
        float* __restrict__ out) {
    const int lane = threadIdx.x & 63;
    const int wave = threadIdx.x >> 6;
    const int n  = blockIdx.x * 64 + lane;   // point id; block spans one b
    const int b  = n >> 10;
    const int hw = n & 1023;

    // x_flat[n][d] = latents[b][d][hw]; consecutive lanes -> consecutive hw
    const float* xb = latents + (size_t)b * C_DIM * HW + hw;
    float x[C_DIM];
    #pragma unroll
    for (int d = 0; d < C_DIM; ++d) x[d] = xb[(size_t)d * HW];

    const float A = np_pairwise_sumsq64(x);

    float best = 3.0e38f;
    int bidx = 0;
    // SGPR-resident slice base -> uniform addresses -> s_load for cb/csum
    const int k0 = __builtin_amdgcn_readfirstlane(wave << 8);
    for (int kk = 0; kk < 256; ++kk) {
        const int k = k0 + kk;
        const float* cbk = cb + (k << 6);
        float m = 0.0f;                       // sequential ascending-d FMA chain
        #pragma unroll
        for (int d = 0; d < C_DIM; ++d) m = __fmaf_rn(x[d], cbk[d], m);
        float dist = __fsub_rn(__fadd_rn(A, csum[k]), __fmul_rn(2.0f, m));
        bool lt = dist < best;                // strict <: first-min within slice
        bidx = lt ? k : bidx;
        best = lt ? dist : best;
    }

    __shared__ float sd[4][64];
    __shared__ int   sk[4][64];
    __shared__ int   fk[64];
    sd[wave][lane] = best;
    sk[wave][lane] = bidx;
    __syncthreads();

    if (wave == 0) {
        float bd = sd[0][lane];
        int   bk = sk[0][lane];
        #pragma unroll
        for (int w = 1; w < 4; ++w) {
            float d2 = sd[w][lane];
            int   k2 = sk[w][lane];
            if (d2 < bd || (d2 == bd && k2 < bk)) { bd = d2; bk = k2; }
        }
        fk[lane] = bk;
        out[OUT_I_OFF + n] = (float)bk;       // 64 contiguous floats per block
        atomicAdd(&hist[bk], 1u);

        // SSE contribution in f64
        const float* cq = cb + (bk << 6);
        double e = 0.0;
        #pragma unroll
        for (int d = 0; d < C_DIM; ++d) {
            double df = (double)x[d] - (double)cq[d];
            e = fma(df, df, e);
        }
        #pragma unroll
        for (int off = 32; off > 0; off >>= 1) e += __shfl_down(e, off, 64);
        if (lane == 0) atomicAdd(sse, e);
    }
    __syncthreads();

    // Quantized slice: out[b][c][hwp] = cb[fk[hwp]][c], 64 c x 64 hw.
    // Thread t: hwp = lane, c = wave + 4*i -> stores contiguous in hw.
    const int myk = fk[lane];
    const size_t obase = (size_t)OUT_Q_OFF + (size_t)b * (C_DIM * HW) + hw;
    #pragma unroll
    for (int i = 0; i < 16; ++i) {
        int c = wave + (i << 2);
        out[obase + (size_t)c * HW] = cb[(myk << 6) + c];
    }
}

// Finalize: perplexity from histogram, vq_loss from SSE.
__global__ void vq_final(const unsigned int* __restrict__ hist,
                         const double* __restrict__ sse,
                         float* __restrict__ out) {
    __shared__ double red[256];
    int t = threadIdx.x;
    double s = 0.0;
    for (int i = t; i < K_CODES; i += 256) {
        double p = (double)hist[i] / (double)N_PTS;
        s += p * log(p + 1e-10);
    }
    red[t] = s;
    __syncthreads();
    for (int w = 128; w > 0; w >>= 1) {
        if (t < w) red[t] += red[t + w];
        __syncthreads();
    }
    if (t == 0) {
        out[OUT_P_OFF] = (float)exp(-red[0]);
        out[0] = (float)(1.25 * sse[0] / (double)Q_ELEMS);
    }
}

extern "C" void kernel_launch(void* const* d_in, const int* in_sizes, int n_in,
                              void* d_out, int out_size, void* d_ws, size_t ws_size,
                              hipStream_t stream) {
    const float* latents = (const float*)d_in[0];
    const float* cb      = (const float*)d_in[1];
    float* out = (float*)d_out;
    char* ws = (char*)d_ws;

    unsigned int* hist = (unsigned int*)(ws + WS_HIST);
    double*       sse  = (double*)(ws + WS_SSE);
    float*        csum = (float*)(ws + WS_CSUM);

    // zero histogram + sse accumulator (contiguous at ws start)
    hipMemsetAsync(ws, 0, 4096 + 8, stream);

    vq_prep <<<4, 256, 0, stream>>>(cb, csum);
    vq_main <<<N_PTS / 64, 256, 0, stream>>>(latents, cb, csum, hist, sse, out);
    vq_final<<<1, 256, 0, stream>>>(hist, sse, out);
}

// Round 5
// 223.268 us; speedup vs baseline: 2.4970x; 1.0403x over previous
//
#include <hip/hip_runtime.h>

// Problem constants
#define N_PTS   65536      // B*H*W = 64*32*32
#define K_CODES 1024
#define C_DIM   64
#define HW      1024
#define Q_ELEMS 4194304

// d_out layout (float32): [vq_loss(1) | quantized(4194304) | perplexity(1) | indices(65536)]
#define OUT_Q_OFF 1
#define OUT_P_OFF 4194305
#define OUT_I_OFF 4194306

// ws layout (bytes)
#define WS_HIST 0          // 1024 u32    (4096)
#define WS_SSE  4096       // 1 double    (8)
#define WS_CSUM 8192       // 1024 f32    (4096)
#define WS_CBH  16384      // 65536 bf16  (131072)
#define WS_CBL  147456     // 65536 bf16  (131072)

// Screen-certainty thresholds. Worst-case bound: screen err <= ~2.4e-5 (3-pass
// split-bf16, pairwise), ref f32 rounding <= 2.4e-5, B-variation ~3e-5.
#define EPS_A 2.0e-4f      // point ambiguous if m2-m1 <= EPS_A
#define EPS_T 4.0e-4f      // rescan tiles with tilemin <= m1+EPS_T

typedef float f32x16 __attribute__((ext_vector_type(16)));
typedef short bf16x8 __attribute__((ext_vector_type(8)));

__device__ __forceinline__ unsigned short bf16rn(float f) {
    unsigned int u = __float_as_uint(f);
    return (unsigned short)((u + 0x7FFFu + ((u >> 16) & 1u)) >> 16);
}
__device__ __forceinline__ float bf16tof(unsigned short h) {
    return __uint_as_float(((unsigned int)h) << 16);
}

// numpy pairwise sum (n=64): 8 accumulators striding 8, then pairwise combine.
__device__ __forceinline__ float np_pairwise_sumsq64(const float* a) {
    float r[8];
    #pragma unroll
    for (int j = 0; j < 8; ++j) r[j] = __fmul_rn(a[j], a[j]);
    #pragma unroll
    for (int i = 8; i < 64; i += 8) {
        #pragma unroll
        for (int j = 0; j < 8; ++j)
            r[j] = __fadd_rn(r[j], __fmul_rn(a[i + j], a[i + j]));
    }
    return __fadd_rn(__fadd_rn(__fadd_rn(r[0], r[1]), __fadd_rn(r[2], r[3])),
                     __fadd_rn(__fadd_rn(r[4], r[5]), __fadd_rn(r[6], r[7])));
}

// Prep: csum (pairwise f32) + split-bf16 codebook (hi/lo).
__global__ void vq_prep(const float* __restrict__ cb, float* __restrict__ csum,
                        unsigned short* __restrict__ cbh, unsigned short* __restrict__ cbl) {
    int k = blockIdx.x * 256 + threadIdx.x;   // grid = 4 blocks covers 1024
    const float* row = cb + k * C_DIM;
    csum[k] = np_pairwise_sumsq64(row);
    #pragma unroll 8
    for (int d = 0; d < C_DIM; ++d) {
        float f = row[d];
        unsigned short h = bf16rn(f);
        cbh[k * C_DIM + d] = h;
        cbl[k * C_DIM + d] = bf16rn(f - bf16tof(h));
    }
}

// Main: MFMA screen (3-pass split-bf16) + guaranteed exact rescan of ambiguous
// points over candidate tiles + all fused outputs.
// Block = 256 thr = 4 waves; block owns 128 points (wave w: points 32w..32w+31).
// A = codes (32 rows), B = points (32 cols), K=64 via 4 chunks of 16.
__global__ __launch_bounds__(256, 2) void vq_main(
        const float* __restrict__ latents,
        const float* __restrict__ cb,
        const float* __restrict__ csum,
        const unsigned short* __restrict__ cbh,
        const unsigned short* __restrict__ cbl,
        unsigned int* __restrict__ hist,
        double* __restrict__ sse,
        float* __restrict__ out) {
    __shared__ float xs[128 * 65];            // x tile, stride 65 (conflict-free)
    __shared__ float tmin[32][128];           // per-(tile,point) screen min
    __shared__ float m1f[128], m2f[128];
    __shared__ int   i1s[128], fk[128];
    __shared__ int   ambig[128], acount;
    __shared__ unsigned long long red[256];
    __shared__ double dred[128];

    const int tid  = threadIdx.x;
    const int lane = tid & 63, wave = tid >> 6;
    const int n0 = blockIdx.x * 128;
    const int b = n0 >> 10, hw0 = n0 & 1023;
    const float* xg = latents + (size_t)b * C_DIM * HW + hw0;

    // Stage x[p][d] (p=0..127 block points), coalesced global, LDS stride 65.
    for (int i = tid; i < 128 * 64; i += 256) {
        int p = i & 127, d = i >> 7;
        xs[p * 65 + d] = xg[(size_t)d * HW + p];
    }
    if (tid == 0) acount = 0;
    __syncthreads();

    // B-frags (points) from LDS: col = lane&31 -> point, k = (lane>>5)*8+j.
    const int l31 = lane & 31, half = lane >> 5;
    const int pb = (wave << 5) + l31;         // this lane's block-point
    bf16x8 xh[4], xl[4];
    #pragma unroll
    for (int c = 0; c < 4; ++c)
        #pragma unroll
        for (int j = 0; j < 8; ++j) {
            float f = xs[pb * 65 + c * 16 + half * 8 + j];
            unsigned short h = bf16rn(f);
            xh[c][j] = (short)h;
            xl[c][j] = (short)bf16rn(f - bf16tof(h));
        }

    float m1 = 3e38f, m2 = 3e38f;
    int i1 = 0;
    const int RC[16] = {0,1,2,3,8,9,10,11,16,17,18,19,24,25,26,27};
    const int rh4 = half * 4;                 // C/D row = RC[reg] + 4*(lane>>5)
    const unsigned short* ah0 = cbh + (size_t)l31 * 64 + half * 8;
    const unsigned short* al0 = cbl + (size_t)l31 * 64 + half * 8;

    for (int t = 0; t < 32; ++t) {            // 32 code-tiles of 32 codes
        const unsigned short* ah = ah0 + (size_t)t * 32 * 64;
        const unsigned short* al = al0 + (size_t)t * 32 * 64;
        bf16x8 ch[4], cl[4];
        #pragma unroll
        for (int c = 0; c < 4; ++c) {
            ch[c] = *(const bf16x8*)(ah + c * 16);
            cl[c] = *(const bf16x8*)(al + c * 16);
        }
        f32x16 acc;
        #pragma unroll
        for (int r = 0; r < 16; ++r) acc[r] = 0.0f;
        #pragma unroll
        for (int c = 0; c < 4; ++c) {
            acc = __builtin_amdgcn_mfma_f32_32x32x16_bf16(ch[c], xh[c], acc, 0, 0, 0);
            acc = __builtin_amdgcn_mfma_f32_32x32x16_bf16(ch[c], xl[c], acc, 0, 0, 0);
            acc = __builtin_amdgcn_mfma_f32_32x32x16_bf16(cl[c], xh[c], acc, 0, 0, 0);
        }
        float tl = 3e38f;
        const int tb = t << 5;
        #pragma unroll
        for (int r = 0; r < 16; ++r) {
            float s = __fmaf_rn(-2.0f, acc[r], 0.5f);   // 0.5 - 2*m (B folded into eps)
            int k = tb + RC[r] + rh4;
            m2 = fminf(m2, fmaxf(m1, s));
            i1 = (s < m1) ? k : i1;
            m1 = fminf(m1, s);
            tl = fminf(tl, s);
        }
        tl = fminf(tl, __shfl_xor(tl, 32, 64));
        if (half == 0) tmin[t][pb] = tl;
    }
    // merge the two half-wave row-sets of each point
    {
        float m1o = __shfl_xor(m1, 32, 64);
        float m2o = __shfl_xor(m2, 32, 64);
        int   i1o = __shfl_xor(i1, 32, 64);
        m2 = fminf(fminf(m2, m2o), fmaxf(m1, m1o));
        i1 = (m1o < m1) ? i1o : i1;
        m1 = fminf(m1, m1o);
        if (half == 0) { m1f[pb] = m1; m2f[pb] = m2; i1s[pb] = i1; }
    }
    __syncthreads();

    // ambiguity test
    if (tid < 128) {
        fk[tid] = i1s[tid];
        if (m2f[tid] - m1f[tid] <= EPS_A) {
            int a = atomicAdd(&acount, 1);
            ambig[a] = tid;
        }
    }
    __syncthreads();

    // exact rescan (reference-bit-exact) of ambiguous points, candidate tiles only
    for (int a = 0; a < acount; ++a) {
        int p = ambig[a];
        const float* xrow = &xs[p * 65];
        float A = np_pairwise_sumsq64(xrow);
        float thr = m1f[p] + EPS_T;
        unsigned long long best = ~0ULL;
        for (int t = 0; t < 32; ++t) {
            if (tmin[t][p] <= thr) {          // block-uniform branch
                if (tid < 32) {
                    int k = (t << 5) + tid;
                    const float* crow = cb + (size_t)k * 64;
                    float m = 0.0f;
                    #pragma unroll
                    for (int d = 0; d < 64; ++d) m = __fmaf_rn(xrow[d], crow[d], m);
                    float D = __fsub_rn(__fadd_rn(A, csum[k]), __fmul_rn(2.0f, m));
                    unsigned long long key =
                        ((unsigned long long)__float_as_uint(D) << 10) | (unsigned)k;
                    best = (key < best) ? key : best;
                }
            }
        }
        red[tid] = best;
        __syncthreads();
        for (int w = 128; w >= 1; w >>= 1) {
            if (tid < w) { if (red[tid + w] < red[tid]) red[tid] = red[tid + w]; }
            __syncthreads();
        }
        if (tid == 0) fk[p] = (int)(red[0] & 1023ULL);
        __syncthreads();
    }

    // outputs: indices + histogram
    if (tid < 128) {
        out[OUT_I_OFF + n0 + tid] = (float)fk[tid];
        atomicAdd(&hist[fk[tid]], 1u);
    }
    // sse (f64)
    if (tid < 128) {
        const float* crow = cb + (size_t)fk[tid] * 64;
        const float* xrow = &xs[tid * 65];
        double e = 0.0;
        #pragma unroll
        for (int d = 0; d < 64; ++d) {
            double df = (double)xrow[d] - (double)crow[d];
            e = fma(df, df, e);
        }
        dred[tid] = e;
    }
    __syncthreads();
    if (tid < 64) {
        double v = dred[tid] + dred[tid + 64];
        #pragma unroll
        for (int off = 32; off > 0; off >>= 1) v += __shfl_down(v, off, 64);
        if (tid == 0) atomicAdd(sse, v);
    }
    // quantized [B,C,H,W]: coalesced 128-float rows per c
    for (int i = tid; i < 128 * 64; i += 256) {
        int p = i & 127, c = i >> 7;
        out[OUT_Q_OFF + (size_t)b * 65536 + (size_t)c * HW + hw0 + p] =
            cb[(size_t)fk[p] * 64 + c];
    }
}

// Finalize: perplexity from histogram, vq_loss from SSE.
__global__ void vq_final(const unsigned int* __restrict__ hist,
                         const double* __restrict__ sse,
                         float* __restrict__ out) {
    __shared__ double red[256];
    int t = threadIdx.x;
    double s = 0.0;
    for (int i = t; i < K_CODES; i += 256) {
        double p = (double)hist[i] / (double)N_PTS;
        s += p * log(p + 1e-10);
    }
    red[t] = s;
    __syncthreads();
    for (int w = 128; w > 0; w >>= 1) {
        if (t < w) red[t] += red[t + w];
        __syncthreads();
    }
    if (t == 0) {
        out[OUT_P_OFF] = (float)exp(-red[0]);
        out[0] = (float)(1.25 * sse[0] / (double)Q_ELEMS);
    }
}

extern "C" void kernel_launch(void* const* d_in, const int* in_sizes, int n_in,
                              void* d_out, int out_size, void* d_ws, size_t ws_size,
                              hipStream_t stream) {
    const float* latents = (const float*)d_in[0];
    const float* cb      = (const float*)d_in[1];
    float* out = (float*)d_out;
    char* ws = (char*)d_ws;

    unsigned int*   hist = (unsigned int*)(ws + WS_HIST);
    double*         sse  = (double*)(ws + WS_SSE);
    float*          csum = (float*)(ws + WS_CSUM);
    unsigned short* cbh  = (unsigned short*)(ws + WS_CBH);
    unsigned short* cbl  = (unsigned short*)(ws + WS_CBL);

    hipMemsetAsync(ws, 0, 4096 + 8, stream);  // hist + sse

    vq_prep <<<4, 256, 0, stream>>>(cb, csum, cbh, cbl);
    vq_main <<<N_PTS / 128, 256, 0, stream>>>(latents, cb, csum, cbh, cbl, hist, sse, out);
    vq_final<<<1, 256, 0, stream>>>(hist, sse, out);
}